// Round 1
// baseline (169.965 us; speedup 1.0000x reference)
//
#include <hip/hip_runtime.h>

// Problem: mean(|box5(x) - box5(y)|), box5 = 5x5 uniform conv, pad=4.
// Identity: box(x)-box(y) = box(x-y). Separable: vertical rolling sum in
// registers (5-row LDS ring for history), horizontal 5-tap via padded LDS row.
// B=64, H=W=512, out spatial 516x516.

#define IMG_W 512
#define IMG_H 512
#define OUT_W 516
#define OUT_H 516
#define TR    16      // output rows per block strip
#define NT    256     // threads per block (each owns 2 columns)

__global__ __launch_bounds__(NT) void box_loss_kernel(
    const float* __restrict__ x, const float* __restrict__ y,
    float* __restrict__ partial)
{
    __shared__ float ring[5][IMG_W];        // 10240 B: d-row history, thread-private columns
    __shared__ float vbuf[2][OUT_W + 4];    // 4160 B: padded vertical sums (double-buffered)
    __shared__ float wsum[NT / 64];

    const int t  = threadIdx.x;             // 0..255
    const int b  = blockIdx.y;              // batch
    const int i0 = blockIdx.x * TR;         // first output row of this strip
    const int c0 = 2 * t;                   // this thread's two columns

    const float* xb = x + (size_t)b * IMG_W * IMG_H;
    const float* yb = y + (size_t)b * IMG_W * IMG_H;

    // zero-init ring (thread-private columns, no barrier needed)
    #pragma unroll
    for (int s = 0; s < 5; ++s) {
        ring[s][c0] = 0.f; ring[s][c0 + 1] = 0.f;
    }
    // zero pad lanes of vbuf (covered by first __syncthreads below)
    if (t < 4) {
        vbuf[0][t] = 0.f;         vbuf[1][t] = 0.f;
        vbuf[0][OUT_W + t] = 0.f; vbuf[1][OUT_W + t] = 0.f;
    }

    // warm-up: accumulate input rows i0-4 .. i0-1 into v, stash in ring
    float v0 = 0.f, v1 = 0.f;
    for (int r = i0 - 4; r < i0; ++r) {
        float d0 = 0.f, d1 = 0.f;
        if (r >= 0) {  // r < IMG_H always (i0 <= 512 => r <= 511)
            float2 xv = *(const float2*)(xb + (size_t)r * IMG_W + c0);
            float2 yv = *(const float2*)(yb + (size_t)r * IMG_W + c0);
            d0 = xv.x - yv.x; d1 = xv.y - yv.y;
        }
        int slot = (r + 5) % 5;  // r >= -4 so r+5 >= 1
        ring[slot][c0] = d0; ring[slot][c0 + 1] = d1;
        v0 += d0; v1 += d1;
    }

    const int nrows = min(TR, OUT_H - i0);
    float acc = 0.f;
    int buf = 0;
    for (int ii = 0; ii < nrows; ++ii) {
        const int i = i0 + ii;
        // roll vertical window: add row i (0 if beyond image), drop row i-5
        float d0 = 0.f, d1 = 0.f;
        if (i < IMG_H) {
            float2 xv = *(const float2*)(xb + (size_t)i * IMG_W + c0);
            float2 yv = *(const float2*)(yb + (size_t)i * IMG_W + c0);
            d0 = xv.x - yv.x; d1 = xv.y - yv.y;
        }
        const int slot = i % 5;
        float o0 = ring[slot][c0], o1 = ring[slot][c0 + 1];
        v0 += d0 - o0; v1 += d1 - o1;
        ring[slot][c0] = d0; ring[slot][c0 + 1] = d1;

        // publish v for horizontal pass (padded by 4 zeros each side)
        vbuf[buf][4 + c0]     = v0;
        vbuf[buf][4 + c0 + 1] = v1;
        __syncthreads();

        const float* __restrict__ vb = vbuf[buf];
        float s0 = vb[t]     + vb[t + 1]   + vb[t + 2]   + vb[t + 3]   + vb[t + 4];
        float s1 = vb[t+256] + vb[t + 257] + vb[t + 258] + vb[t + 259] + vb[t + 260];
        acc += fabsf(s0) + fabsf(s1);
        if (t < 4) {
            float s2 = vb[t+512] + vb[t+513] + vb[t+514] + vb[t+515] + vb[t+516];
            acc += fabsf(s2);
        }
        buf ^= 1;  // next iter writes other buffer; barrier above protects reuse
    }

    // block reduction: wave shuffle, then cross-wave via LDS
    #pragma unroll
    for (int off = 32; off > 0; off >>= 1)
        acc += __shfl_down(acc, off, 64);
    if ((t & 63) == 0) wsum[t >> 6] = acc;
    __syncthreads();
    if (t == 0) {
        float s = wsum[0] + wsum[1] + wsum[2] + wsum[3];
        atomicAdd(partial, s);
    }
}

__global__ void finalize_kernel(const float* __restrict__ partial,
                                float* __restrict__ out)
{
    // mean over 64*516*516 outputs, each scaled by 1/25
    out[0] = partial[0] * (1.0f / (25.0f * 64.0f * 516.0f * 516.0f));
}

extern "C" void kernel_launch(void* const* d_in, const int* in_sizes, int n_in,
                              void* d_out, int out_size, void* d_ws, size_t ws_size,
                              hipStream_t stream) {
    const float* x = (const float*)d_in[0];
    const float* y = (const float*)d_in[1];
    float* out = (float*)d_out;
    float* ws  = (float*)d_ws;

    hipMemsetAsync(ws, 0, sizeof(float), stream);  // capturable memset node

    dim3 grid((OUT_H + TR - 1) / TR, 64);          // 33 x 64 = 2112 blocks
    box_loss_kernel<<<grid, NT, 0, stream>>>(x, y, ws);
    finalize_kernel<<<1, 1, 0, stream>>>(ws, out);
}